// Round 5
// baseline (850.640 us; speedup 1.0000x reference)
//
#include <hip/hip_runtime.h>
#include <hip/hip_bf16.h>
#include <math.h>

// ---------------------------------------------------------------------------
// ContextualAttention: y[b,p,q] = softmax_p( 10 * mm[p] * T[p][q] / denom[b,p] ) * mm[p]
//   S[b][u][v] = Σ_c b_in[b,c,u] * f_in[b,c,v]   (K=128 GEMM, bf16x2-split MFMA)
//   T[p][q] = Σ_s S[p+s][q+s], s = 64dy+dx (9 diagonal taps, masked at edges)
//
// Diagonal layout: SD[t][(t-col)&4095]. All 9 taps of T[p][q] lie on diagonal
// d = p-q: tap = SD[t+s][d]. k_pass: thread owns TWO diagonals (d0, d0+1),
// walks t with f32x2 loads; 3-deep software pipeline (5 rolling f32x2 regs per
// band) keeps ~9 loads in flight per thread; coef staged in LDS (no per-step
// uniform global loads). Denominator via wave-private LDS window (2-way ds_add,
// free) flushed by global atomics; k_scale streams out *= linv[q].
// ---------------------------------------------------------------------------

typedef float f32x2 __attribute__((ext_vector_type(2)));
typedef float f32x4 __attribute__((ext_vector_type(4)));
typedef short bf16x8 __attribute__((ext_vector_type(8)));

#define NB 4
#define NC 128
#define NP 4096ull       // 64*64 spatial positions
#define LOG2E_SCALE 14.426950408889634f   // 10 * log2(e)
#define EPS_TERM (1152.0f * 1e-4f)
#define TCH 128          // t-chunk per k_pass block

// ---- workspace layout (bytes) ----
#define SZ_S      (4ull * NP * NP * 4ull)            // 268435456 (SD, diagonal-major)
#define SZ_BT     (4ull * NP * NC * 2ull)            // 4194304 (bf16 [b][u][c])
#define OFF_S     1024ull
#define OFF_BT_HI (OFF_S + SZ_S + 1024ull)
#define OFF_BT_LO (OFF_BT_HI + SZ_BT)
#define OFF_FT_HI (OFF_BT_LO + SZ_BT)
#define OFF_FT_LO (OFF_FT_HI + SZ_BT)
#define OFF_NORM2 (OFF_FT_LO + SZ_BT)
#define OFF_COEF  (OFF_NORM2 + 4ull * NP * 4ull)     // 4*4096 f32
#define OFF_MM    (OFF_COEF + 4ull * NP * 4ull)      // 4096 f32
#define OFF_GSUM  (OFF_MM + NP * 4ull)               // 4*4096 f32 (softmax denom)
#define OFF_LINV  (OFF_GSUM + 4ull * NP * 4ull)      // 4*4096 f32

// ---------------------------------------------------------------------------
// norm2[b][u] = sum_c b_in[b,c,u]^2
__global__ __launch_bounds__(256) void k_norm2(const float* __restrict__ bin,
                                               float* __restrict__ norm2) {
    int idx = blockIdx.x * 256 + threadIdx.x;       // 16384 = 4*4096
    int b = idx >> 12, u = idx & 4095;
    const float* src = bin + (size_t)b * NC * NP + u;
    float s = 0.f;
#pragma unroll 8
    for (int c = 0; c < NC; ++c) { float x = src[(size_t)c * NP]; s += x * x; }
    norm2[idx] = s;
}

// coef[b][p] = mm[p] * 10*log2(e) / sqrt(boxsum3x3(norm2) + 1152*EPS)
// Also zeroes gsum (softmax denominator accumulator, same 4*4096 shape).
__global__ __launch_bounds__(256) void k_coef(const float* __restrict__ norm2,
                                              const float* __restrict__ mask,
                                              float* __restrict__ coef,
                                              float* __restrict__ mmArr,
                                              float* __restrict__ gsum) {
    int idx = blockIdx.x * 256 + threadIdx.x;       // 16384
    int b = idx >> 12, p = idx & 4095;
    int ph = p >> 6, pw = p & 63;
    float ns = 0.f, ms = 0.f;
#pragma unroll
    for (int dy = -1; dy <= 1; ++dy)
#pragma unroll
        for (int dx = -1; dx <= 1; ++dx) {
            int hh = ph + dy, ww = pw + dx;
            if ((unsigned)hh < 64u && (unsigned)ww < 64u) {
                ns += norm2[b * 4096 + hh * 64 + ww];
                ms += mask[(size_t)(hh * 512 + ww) * 8];
            }
        }
    float mmv = (ms == 0.f) ? 1.f : 0.f;
    coef[idx] = mmv * LOG2E_SCALE / sqrtf(ns + EPS_TERM);
    if (b == 0) mmArr[p] = mmv;
    gsum[idx] = 0.f;
}

// ---------------------------------------------------------------------------
// Transpose [c][u] f32 -> [u][c] bf16 hi/lo split (per batch, per input array)
__global__ __launch_bounds__(256) void k_convert(const float* __restrict__ fin,
                                                 const float* __restrict__ bin,
                                                 __bf16* __restrict__ bt_hi, __bf16* __restrict__ bt_lo,
                                                 __bf16* __restrict__ ft_hi, __bf16* __restrict__ ft_lo) {
    __shared__ float tile[64][65];
    int u0 = blockIdx.x * 64;
    int k0 = blockIdx.y * 64;
    int z = blockIdx.z;                  // 0..7 : (batch<<1)|arr
    int arr = z & 1, b = z >> 1;
    const float* src = (arr ? fin : bin) + (size_t)b * NC * NP;
    __bf16* dhi = (arr ? ft_hi : bt_hi) + (size_t)b * NP * NC;
    __bf16* dlo = (arr ? ft_lo : bt_lo) + (size_t)b * NP * NC;
    int t = threadIdx.x;
#pragma unroll
    for (int i = 0; i < 16; ++i) {
        int lin = i * 256 + t;
        int kl = lin >> 6, ul = lin & 63;
        tile[kl][ul] = src[(size_t)(k0 + kl) * NP + u0 + ul];
    }
    __syncthreads();
#pragma unroll
    for (int i = 0; i < 16; ++i) {
        int lin = i * 256 + t;
        int ul = lin >> 6, kl = lin & 63;   // consecutive t -> consecutive kl (coalesced out)
        float x = tile[kl][ul];
        __bf16 h = (__bf16)x;
        float hf = (float)h;
        __bf16 l = (__bf16)(x - hf);
        size_t o = (size_t)(u0 + ul) * NC + (k0 + kl);
        dhi[o] = h; dlo[o] = l;
    }
}

// ---------------------------------------------------------------------------
// SD[b][row][(row-col)&4095] = sum_c bT[row][c] * fT[col][c]
// 16x16x32 bf16 MFMA, 3-term hi/lo split. Block: 256 thr = 4 waves (2x2),
// tile 128x128; each wave 64x64 (4x4 MFMA tiles). Epilogue writes the
// DIAGONAL-MAJOR layout (same 64B-segment coalescing as row-major).
__global__ __launch_bounds__(256) void k_matmul(const __bf16* __restrict__ bt_hi,
                                                const __bf16* __restrict__ bt_lo,
                                                const __bf16* __restrict__ ft_hi,
                                                const __bf16* __restrict__ ft_lo,
                                                float* __restrict__ S) {
    int t = threadIdx.x;
    int lane = t & 63;
    int w = t >> 6;
    int b = blockIdx.z;
    int m_base = blockIdx.y * 128 + (w >> 1) * 64;
    int n_base = blockIdx.x * 128 + (w & 1) * 64;
    int l15 = lane & 15;
    int quad = lane >> 4;
    size_t bo = (size_t)b * NP * NC;
    const __bf16* Ah = bt_hi + bo;
    const __bf16* Al = bt_lo + bo;
    const __bf16* Bh = ft_hi + bo;
    const __bf16* Bl = ft_lo + bo;

    f32x4 acc[4][4];
#pragma unroll
    for (int i = 0; i < 4; ++i)
#pragma unroll
        for (int j = 0; j < 4; ++j) acc[i][j] = (f32x4){0.f, 0.f, 0.f, 0.f};

#pragma unroll
    for (int ks = 0; ks < 4; ++ks) {
        int k = ks * 32 + quad * 8;      // A[m=l15][k..k+7], contiguous in memory
        bf16x8 ah[4], al[4], bh[4], bl[4];
#pragma unroll
        for (int mt = 0; mt < 4; ++mt) {
            size_t o = (size_t)(m_base + mt * 16 + l15) * NC + k;
            ah[mt] = *(const bf16x8*)(Ah + o);
            al[mt] = *(const bf16x8*)(Al + o);
        }
#pragma unroll
        for (int nt = 0; nt < 4; ++nt) {
            size_t o = (size_t)(n_base + nt * 16 + l15) * NC + k;
            bh[nt] = *(const bf16x8*)(Bh + o);
            bl[nt] = *(const bf16x8*)(Bl + o);
        }
#pragma unroll
        for (int mt = 0; mt < 4; ++mt)
#pragma unroll
            for (int nt = 0; nt < 4; ++nt) {
                acc[mt][nt] = __builtin_amdgcn_mfma_f32_16x16x32_bf16(ah[mt], bh[nt], acc[mt][nt], 0, 0, 0);
                acc[mt][nt] = __builtin_amdgcn_mfma_f32_16x16x32_bf16(ah[mt], bl[nt], acc[mt][nt], 0, 0, 0);
                acc[mt][nt] = __builtin_amdgcn_mfma_f32_16x16x32_bf16(al[mt], bh[nt], acc[mt][nt], 0, 0, 0);
            }
    }
    // C/D layout (m89-verified): col = lane&15, row = quad*4 + reg
    float* Sb = S + (size_t)b * NP * NP;
#pragma unroll
    for (int mt = 0; mt < 4; ++mt)
#pragma unroll
        for (int nt = 0; nt < 4; ++nt) {
            int col = n_base + nt * 16 + l15;
            int row0 = m_base + mt * 16 + quad * 4;
#pragma unroll
            for (int r = 0; r < 4; ++r) {
                int row = row0 + r;
                Sb[(size_t)row * NP + ((row - col) & 4095)] = acc[mt][nt][r];
            }
        }
}

// ---------------------------------------------------------------------------
// Fused stencil+exp+write pass along diagonals. Thread owns diagonals
// (d0, d0+1), walks t in [t0, t0+TCH). Per band (dy=-1,0,+1) a 5-register
// f32x2 rolling window {m1,z0,p1,f1,f2}: the load issued at step ti lands in
// f2 and is consumed as p1 at step ti+3 -> ~9 f32x2 loads in flight/thread
// (3-deep pipeline; unroll 8 turns rotation into renaming). coef chunk staged
// in LDS; mm derived from coef>0. Denominator into wave-private LDS window
// (stride-2 ds_add = 2-way, free), flushed by global atomics.
__global__ __launch_bounds__(256) void k_pass(const float* __restrict__ SD,
                                              const float* __restrict__ coef,
                                              float* __restrict__ out,
                                              float* __restrict__ gsum) {
    // XCD-chunked bijective swizzle (1024 blocks % 8 == 0)
    int orig = blockIdx.x;
    int wg = (orig & 7) * 128 + (orig >> 3);
    int tc = wg & 31;               // t-chunk   0..31 (TCH=128)
    int dc = (wg >> 5) & 7;         // d-chunk   0..7  (512 diagonals)
    int b  = wg >> 8;               // batch     0..3
    int t0 = tc * TCH;
    int lane = threadIdx.x & 63;
    int w = threadIdx.x >> 6;
    int dwb = dc * 512 + w * 128;   // wave's diagonal base (128 diagonals/wave)
    int d0 = dwb + 2 * lane;        // this thread's even diagonal pair base
    const float* SDb = SD + (size_t)b * NP * NP;
    float* outb = out + (size_t)b * NP * NP;

    __shared__ float win[4][TCH + 128];   // wave-private q-window
    __shared__ float cfs[TCH];
    for (int s = lane; s < TCH + 128; s += 64) win[w][s] = 0.f;
    if (threadIdx.x < TCH) cfs[threadIdx.x] = coef[(b << 12) + t0 + threadIdx.x];
    __syncthreads();

    // Row-clamped f32x2 load at this thread's diagonal pair (clamped rows are
    // always masked by uv/dv/lv/rv validity below).
#define ROWC(i) ((i) < 0 ? 0 : ((i) > 4095 ? 4095 : (i)))
#define L2AT(i) (*(const f32x2*)(SDb + (size_t)ROWC(i) * NP + d0))

    // band a = rows t-64+{-1,0,1}, band b = t+{-1,0,1}, band c = t+64+{-1,0,1}
    f32x2 am1 = L2AT(t0 - 65), az0 = L2AT(t0 - 64), ap1 = L2AT(t0 - 63), af1 = L2AT(t0 - 62), af2 = L2AT(t0 - 61);
    f32x2 bm1 = L2AT(t0 - 1),  bz0 = L2AT(t0),      bp1 = L2AT(t0 + 1),  bf1 = L2AT(t0 + 2),  bf2 = L2AT(t0 + 3);
    f32x2 cm1 = L2AT(t0 + 63), cz0 = L2AT(t0 + 64), cp1 = L2AT(t0 + 65), cf1 = L2AT(t0 + 66), cf2 = L2AT(t0 + 67);

#pragma unroll 8
    for (int ti = 0; ti < TCH; ++ti) {
        int t = t0 + ti;
        // issue loads consumed 3 steps from now (enter f2; become p1 at ti+3)
        f32x2 an = L2AT(t - 60);    // = (t+3) - 63
        f32x2 bn = L2AT(t + 4);     // = (t+3) + 1
        f32x2 cn = L2AT(t + 68);    // = (t+3) + 65
        float c = cfs[ti];
        int pw = t & 63, ph = t >> 6;           // wave-uniform
        int q0 = (t - d0) & 4095;
        int q1 = (t - d0 - 1) & 4095;
        int qw0 = q0 & 63, qh0 = q0 >> 6;
        int qw1 = q1 & 63, qh1 = q1 >> 6;
        bool lv0 = (pw > 0) & (qw0 > 0),  rv0 = (pw < 63) & (qw0 < 63);
        bool lv1 = (pw > 0) & (qw1 > 0),  rv1 = (pw < 63) & (qw1 < 63);
        bool uv0 = (ph > 0) & (qh0 > 0),  dv0 = (ph < 63) & (qh0 < 63);
        bool uv1 = (ph > 0) & (qh1 > 0),  dv1 = (ph < 63) & (qh1 < 63);
        float Va0 = az0.x + (lv0 ? am1.x : 0.f) + (rv0 ? ap1.x : 0.f);
        float Vb0 = bz0.x + (lv0 ? bm1.x : 0.f) + (rv0 ? bp1.x : 0.f);
        float Vc0 = cz0.x + (lv0 ? cm1.x : 0.f) + (rv0 ? cp1.x : 0.f);
        float Va1 = az0.y + (lv1 ? am1.y : 0.f) + (rv1 ? ap1.y : 0.f);
        float Vb1 = bz0.y + (lv1 ? bm1.y : 0.f) + (rv1 ? bp1.y : 0.f);
        float Vc1 = cz0.y + (lv1 ? cm1.y : 0.f) + (rv1 ? cp1.y : 0.f);
        float T0 = Vb0 + (uv0 ? Va0 : 0.f) + (dv0 ? Vc0 : 0.f);
        float T1 = Vb1 + (uv1 ? Va1 : 0.f) + (dv1 ? Vc1 : 0.f);
        float e0 = exp2f(c * T0);               // masked rows: coef=0 -> e=1
        float e1 = exp2f(c * T1);
        atomicAdd(&win[w][ti + 127 - 2 * lane], e0);   // stride-2: 2-way, free
        atomicAdd(&win[w][ti + 126 - 2 * lane], e1);
        float mv = (c > 0.f) ? 1.f : 0.f;
        outb[(size_t)t * NP + q0] = e0 * mv;
        outb[(size_t)t * NP + q1] = e1 * mv;
        am1 = az0; az0 = ap1; ap1 = af1; af1 = af2; af2 = an;
        bm1 = bz0; bz0 = bp1; bp1 = bf1; bf1 = bf2; bf2 = bn;
        cm1 = cz0; cz0 = cp1; cp1 = cf1; cf1 = cf2; cf2 = cn;
    }
#undef L2AT
#undef ROWC
    // flush wave window to global denominator (same wave: ordered, no barrier)
    float* gs = gsum + (b << 12);
    int qb = t0 - dwb - 127;
    for (int s = lane; s < TCH + 127; s += 64)
        atomicAdd(&gs[(qb + s) & 4095], win[w][s]);
}

// linv[b][q] = 1 / gsum[b][q]
__global__ __launch_bounds__(256) void k_linv(const float* __restrict__ gsum,
                                              float* __restrict__ linv) {
    int idx = blockIdx.x * 256 + threadIdx.x;  // 16384
    linv[idx] = 1.0f / gsum[idx];
}

// out[b][p][q] *= linv[b][q]   (pure streaming scale, f32x4)
__global__ __launch_bounds__(256) void k_scale(float* __restrict__ out,
                                               const float* __restrict__ linv) {
    const size_t NV = 4ull * NP * NP / 4ull;   // 16777216 vecs; 32 iters/thread
    for (size_t v = (size_t)blockIdx.x * 256 + threadIdx.x; v < NV; v += 2048ull * 256ull) {
        size_t e0 = v << 2;
        int q = (int)(e0 & 4095);
        int b = (int)(e0 >> 24);
        f32x4 x = *(f32x4*)(out + e0);
        f32x4 L = *(const f32x4*)(linv + ((size_t)b << 12) + q);
        x.x *= L.x; x.y *= L.y; x.z *= L.z; x.w *= L.w;
        *(f32x4*)(out + e0) = x;
    }
}

// ---------------------------------------------------------------------------
extern "C" void kernel_launch(void* const* d_in, const int* in_sizes, int n_in,
                              void* d_out, int out_size, void* d_ws, size_t ws_size,
                              hipStream_t stream) {
    (void)in_sizes; (void)n_in; (void)out_size; (void)ws_size;
    const float* f_in = (const float*)d_in[0];
    const float* b_in = (const float*)d_in[1];
    const float* mask = (const float*)d_in[2];
    float* out = (float*)d_out;
    char* ws = (char*)d_ws;

    float*  S     = (float*)(ws + OFF_S);
    __bf16* bt_hi = (__bf16*)(ws + OFF_BT_HI);
    __bf16* bt_lo = (__bf16*)(ws + OFF_BT_LO);
    __bf16* ft_hi = (__bf16*)(ws + OFF_FT_HI);
    __bf16* ft_lo = (__bf16*)(ws + OFF_FT_LO);
    float*  norm2 = (float*)(ws + OFF_NORM2);
    float*  coef  = (float*)(ws + OFF_COEF);
    float*  mmArr = (float*)(ws + OFF_MM);
    float*  gsum  = (float*)(ws + OFF_GSUM);
    float*  linv  = (float*)(ws + OFF_LINV);

    k_norm2  <<<64, 256, 0, stream>>>(b_in, norm2);
    k_coef   <<<64, 256, 0, stream>>>(norm2, mask, coef, mmArr, gsum);
    k_convert<<<dim3(64, 2, 8), 256, 0, stream>>>(f_in, b_in, bt_hi, bt_lo, ft_hi, ft_lo);
    k_matmul <<<dim3(32, 32, 4), 256, 0, stream>>>(bt_hi, bt_lo, ft_hi, ft_lo, S);
    k_pass   <<<1024, 256, 0, stream>>>(S, coef, out, gsum);
    k_linv   <<<64, 256, 0, stream>>>(gsum, linv);
    k_scale  <<<2048, 256, 0, stream>>>(out, linv);
}